// Round 4
// baseline (1032.559 us; speedup 1.0000x reference)
//
#include <hip/hip_runtime.h>
#include <hip/hip_bf16.h>

// RNN: B=4096, T=1024, H=40, K=41. fp32 compute & state (dtype autodetected).
// Round-14: make weight residency ARITHMETICALLY feasible instead of fighting
// the register allocator (rounds 11-13: VGPR_Count=104 regardless of
// launch_bounds/waves_per_eu/asm pins -> ~173 weight floats/thread can never
// be arch-resident; compiler remats/AGPR-parks them -> per-step reload tax;
// all land 880-990us).
// New structure:
//   1 el per 64-thread block, grid 4096 -> 16 blocks/CU -> 4 waves/SIMD
//   (2x latency hiding vs rounds 11-13). amdgpu_waves_per_eu(4,4): 128 VGPR.
//   kh=lane&1 (K-half), w=lane>>1 (32 workers). Union row-slots wR[4][5]:
//     w<16 : wR[0..2]=L1 rows {3w,3w+1,3w+2}; wR[3]=L2 row 32+w (w<8 only)
//     w>=16: wR[0..1]=L1 rows {48+2(w-16),+1}; wR[2..3]=L2 rows {2(w-16),+1}
//   -> 80 weight floats + 12 scalars + 20 state + misc ~= 127 <= 128. FITS.
//   o-acts (L1 rows 40..79) never hit LDS: producers hold h2o_w2 scalar,
//   c += act*wo in-register; wave row_ror DPP tree (1,2,4,8) + 3 readlane
//   gives the output scalar. Removes divergent op-reads + o-act writes.
//   LDS per wave-step ~17 instrs, every read a <=2-address broadcast (free).
//   Hidden-state sum order identical to rounds 11-13 (same kh-split) ->
//   recurrence numerics unchanged; output row is a tree-sum (noise << bf16
//   output quantum 2^-11).
// Row maps verified: L1 rows 0..79 exactly once (w<16 -> 0..47, w>=16 ->
// 48..79); sA writes rows 0..39 exactly once (w<=12: 3w..3w+2, w13: 39);
// o-rows 40..79 exactly once (w13:{40,41}, w14:{42..44}, w15:{45..47},
// w>=16: {48+2(w-16),+1}); L2 rows 0..39 exactly once (w>=16: 0..31,
// w<8: 32..39); output via reduce. Bank math: reads 2-addr broadcast (free,
// m136); writes <=2-way aliasing (free). 2 barriers/step, 1-wave blocks.

#define B_SZ 4096
#define T_SZ 1024
#define HID  40

typedef unsigned short u16;
typedef unsigned int   u32;
typedef float f4 __attribute__((ext_vector_type(4)));

__device__ __forceinline__ float bf2f(u16 v) {
  union { u32 u; float f; } c; c.u = ((u32)v) << 16; return c.f;
}

template <bool BF>
__device__ __forceinline__ float ldg(const void* p, long i) {
  if (BF) return bf2f(((const u16*)p)[i]);
  return ((const float*)p)[i];
}

template <bool BF>
__device__ __forceinline__ f4 ldg4(const void* p, long i) {
  f4 r;
  r.x = ldg<BF>(p, i + 0);
  r.y = ldg<BF>(p, i + 1);
  r.z = ldg<BF>(p, i + 2);
  r.w = ldg<BF>(p, i + 3);
  return r;
}

// Proven rounds 3-13: true-bf16 weights all have |w| <= 1/sqrt(41) ~ 0.156;
// fp32 data read as bf16 halfwords exceeds 0.2 with P ~ 1-1e-10.
__device__ __forceinline__ bool detect_bf16(const void* w) {
  const u16* p = (const u16*)w;
  bool bf = true;
  for (int i = 0; i < 64; ++i) {
    float f = bf2f(p[i]);
    if (!(fabsf(f) <= 0.2f)) bf = false;
  }
  return bf;
}

// Partner value from lane^1 (quad_perm [1,0,3,2]). VALU pipe, no LDS.
__device__ __forceinline__ float pair_other(float x) {
  return __int_as_float(__builtin_amdgcn_update_dpp(
      0, __float_as_int(x), 0xB1, 0xF, 0xF, true));
}

// x + (x rotated by N within each 16-lane row). CTRL = 0x120|N (row_ror:N).
template <int CTRL>
__device__ __forceinline__ float ror_add(float x) {
  return x + __int_as_float(__builtin_amdgcn_update_dpp(
      0, __float_as_int(x), CTRL, 0xF, 0xF, true));
}

template <bool BF>
__global__ __launch_bounds__(64)
__attribute__((amdgpu_waves_per_eu(4, 4)))   // exactly 4 waves/EU: 128-VGPR
                                             // budget, no occupancy chase
void rnn_kernel(const void* __restrict__ inp,
                const void* __restrict__ h2h_w1, const void* __restrict__ h2h_b1,
                const void* __restrict__ h2h_w2, const void* __restrict__ h2h_b2,
                const void* __restrict__ h2o_w1, const void* __restrict__ h2o_b1,
                const void* __restrict__ h2o_w2, const void* __restrict__ h2o_b2,
                void* __restrict__ out) {
  __shared__ __align__(16) float sH[48];  // hidden state h[0..39] (+pad)
  __shared__ __align__(16) float sA[48];  // h2h-L1 acts a[0..39] (+pad)

  if (detect_bf16(h2h_w1) != BF) return;  // wrong-dtype instantiation exits

  const int tid  = threadIdx.x;
  const int lane = tid & 63;
  const int kh   = lane & 1;          // K-half: 0 -> k 0..19, 1 -> k 20..39
  const int w    = lane >> 1;         // worker 0..31
  const int koff = kh * 20;

  const int nA = (w < 16) ? 3 : 2;                    // L1 rows owned
  const int a0 = (w < 16) ? 3 * w : 48 + 2 * (w - 16);

  // ---- Weights: 4 union row-slots x 5 f4 (K-half) = 80 floats ----
  f4    wR[4][5];
  float wu[3], ba[3], wo[3], bb[2];

  // Phase-A rows (L1): wR[0..nA-1]
#pragma unroll
  for (int q = 0; q < 3; ++q) {
    wu[q] = 0.f; ba[q] = 0.f; wo[q] = 0.f;
    if (q < nA) {
      const int  j  = a0 + q;
      const bool hh = (j < HID);
      const void* w1p = hh ? h2h_w1 : h2o_w1;
      const long  jr  = hh ? j : (j - HID);
      if (kh == 0) {
        wu[q] = ldg<BF>(w1p, jr * 41);
        ba[q] = ldg<BF>(hh ? h2h_b1 : h2o_b1, jr);
        if (!hh) wo[q] = ldg<BF>(h2o_w2, j - HID);  // output-row weight
      }
#pragma unroll
      for (int i = 0; i < 5; ++i)
        wR[q][i] = ldg4<BF>(w1p, jr * 41 + 1 + koff + 4 * i);
    }
  }
  // Phase-B rows (L2): w>=16 -> wR[2..3]; w<8 -> wR[3]
  bb[0] = 0.f; bb[1] = 0.f;
  if (w >= 16) {
    const int b0r = 2 * (w - 16);
#pragma unroll
    for (int q = 0; q < 2; ++q) {
      if (kh == 0) bb[q] = ldg<BF>(h2h_b2, b0r + q);
#pragma unroll
      for (int i = 0; i < 5; ++i)
        wR[2 + q][i] = ldg4<BF>(h2h_w2, (long)(b0r + q) * HID + koff + 4 * i);
    }
  } else if (w < 8) {
    if (kh == 0) bb[0] = ldg<BF>(h2h_b2, 32 + w);
#pragma unroll
    for (int i = 0; i < 5; ++i)
      wR[3][i] = ldg4<BF>(h2h_w2, (long)(32 + w) * HID + koff + 4 * i);
  }
  const float bo = ldg<BF>(h2o_b2, 0);   // output bias (uniform)

  for (int i = tid; i < 48; i += 64) sH[i] = 0.f;
  __syncthreads();

  const long base = (long)blockIdx.x * T_SZ;   // 1 el per block
  float u_cur = ldg<BF>(inp, base);

  const f4* hp = (const f4*)(&sH[koff]);   // state K-half (broadcast read)
  const f4* ap = (const f4*)(&sA[koff]);   // a-acts K-half (broadcast read)

  for (int t = 0; t < T_SZ; ++t) {
    const float u_nxt = (t + 1 < T_SZ) ? ldg<BF>(inp, base + t + 1) : 0.f;

    // ---------- Phase A: layer 1 (80 rows), K-half per thread ----------
    float acts[3];
    float c = 0.f;                       // output-row contribution
    {
      f4 hv[5];
#pragma unroll
      for (int i = 0; i < 5; ++i) hv[i] = hp[i];
#pragma unroll
      for (int q = 0; q < 3; ++q) {
        if (q < nA) {                    // half-wave-uniform (w<16 vs >=16)
          float a = fmaf(u_cur, wu[q], ba[q]);   // kh==1: fmaf(u,0,0) = 0
#pragma unroll
          for (int i = 0; i < 5; ++i) {
            a = fmaf(hv[i].x, wR[q][i].x, a);
            a = fmaf(hv[i].y, wR[q][i].y, a);
            a = fmaf(hv[i].z, wR[q][i].z, a);
            a = fmaf(hv[i].w, wR[q][i].w, a);
          }
          const float s   = a + pair_other(a);    // combine K-halves
          const float act = fmaxf(s, 0.01f * s);  // LeakyReLU(0.01)
          acts[q] = act;
          c = fmaf(act, wo[q], c);      // wo==0 unless o-row && kh==0
        }
      }
    }
    // A-writes: h2h-L1 acts rows 0..39 only (o-acts stay in registers)
    if (kh == 0) {
      if (w <= 12) {
        sA[a0]     = acts[0];
        sA[a0 + 1] = acts[1];
        sA[a0 + 2] = acts[2];
      } else if (w == 13) {
        sA[39] = acts[0];               // rows 40,41 are o-rows
      }
    }
    __syncthreads();   // sA visible; all sH reads done

    // ---------- Output: wave tree-sum of c (no LDS) ----------
    c = ror_add<0x121>(c);   // +ror1
    c = ror_add<0x122>(c);   // +ror2
    c = ror_add<0x124>(c);   // +ror4
    c = ror_add<0x128>(c);   // +ror8 -> each lane holds its 16-row sum
    {
      const float r1 = __int_as_float(__builtin_amdgcn_readlane(__float_as_int(c), 16));
      const float r2 = __int_as_float(__builtin_amdgcn_readlane(__float_as_int(c), 32));
      const float r3 = __int_as_float(__builtin_amdgcn_readlane(__float_as_int(c), 48));
      if (tid == 0) {                    // row 0 (lanes 0..15) contributes 0
        const float v = r1 + r2 + r3 + bo;
        if (BF) ((__hip_bfloat16*)out)[base + t] = __float2bfloat16(v);
        else    ((float*)out)[base + t] = v;
      }
    }

    // ---------- Phase B: layer 2 hidden rows 0..39 ----------
    {
      f4 av[5];
#pragma unroll
      for (int i = 0; i < 5; ++i) av[i] = ap[i];
      if (w >= 16) {                     // rows 2(w-16), 2(w-16)+1
#pragma unroll
        for (int q = 0; q < 2; ++q) {
          float s = bb[q];
#pragma unroll
          for (int i = 0; i < 5; ++i) {
            s = fmaf(av[i].x, wR[2 + q][i].x, s);
            s = fmaf(av[i].y, wR[2 + q][i].y, s);
            s = fmaf(av[i].z, wR[2 + q][i].z, s);
            s = fmaf(av[i].w, wR[2 + q][i].w, s);
          }
          const float v = s + pair_other(s);
          if (kh == 0) sH[2 * (w - 16) + q] = v;
        }
      } else if (w < 8) {                // row 32+w
        float s = bb[0];
#pragma unroll
        for (int i = 0; i < 5; ++i) {
          s = fmaf(av[i].x, wR[3][i].x, s);
          s = fmaf(av[i].y, wR[3][i].y, s);
          s = fmaf(av[i].z, wR[3][i].z, s);
          s = fmaf(av[i].w, wR[3][i].w, s);
        }
        const float v = s + pair_other(s);
        if (kh == 0) sH[32 + w] = v;
      }
    }
    __syncthreads();   // sH update + sA reads done before next step

    u_cur = u_nxt;
  }
}

extern "C" void kernel_launch(void* const* d_in, const int* in_sizes, int n_in,
                              void* d_out, int out_size, void* d_ws, size_t ws_size,
                              hipStream_t stream) {
  (void)in_sizes; (void)n_in; (void)out_size; (void)d_ws; (void)ws_size;
  rnn_kernel<false><<<dim3(B_SZ), dim3(64), 0, stream>>>(
      d_in[0], d_in[1], d_in[2], d_in[3], d_in[4],
      d_in[5], d_in[6], d_in[7], d_in[8], d_out);
  rnn_kernel<true><<<dim3(B_SZ), dim3(64), 0, stream>>>(
      d_in[0], d_in[1], d_in[2], d_in[3], d_in[4],
      d_in[5], d_in[6], d_in[7], d_in[8], d_out);
}

// Round 5
// 742.743 us; speedup vs baseline: 1.3902x; 1.3902x over previous
//
#include <hip/hip_runtime.h>
#include <hip/hip_bf16.h>

// RNN: B=4096, T=1024, H=40, K=41. fp32 compute & state (dtype autodetected).
// Round-15: packed-f32 math on the round-10 champion structure (878us).
// History: R11 (LDS halved, conflicts->0): 904. R12 (1-wave blocks): 935.
// R13 (waves_per_eu 2,2): 955. R14 (1 el/block, demand<=128): 1032 with
// VGPR_Count=64 -- the allocator NEVER keeps big weight arrays live (104/104/
// 104/64 across four attempts); restructuring for residency is a dead end,
// and per-el issue efficiency got worse. R10 remains fastest -> its 4-el
// wave mapping (~51 VALU issues per el-step) is the most issue-efficient.
// This round: ONE variable vs R10 -- inner dot products rewritten over
// float2 ext-vectors so LLVM selects v_pk_fma_f32 (VOP3P packed f32,
// gfx90a+/gfx950): 2 FMAs/instr/lane, halving the dominant FMA issue
// volume (~203 -> ~105 issues/wave-step). Structure, row maps, LDS layout,
// barriers, launch bounds: bit-identical to R10.
//   1024 blocks x 128 thr (2 waves), 4 els/block -> 4 blocks/CU (8 waves/CU).
//   el = lane&3, worker w = wv*16 + (lane>>2)  (0..31).
//   Wave 0 (w 0..15):  A: 3 rows {3w,3w+1,3w+2} (rows 0..47)
//                      B: w<8 -> row 32+w; w==8 -> row 40 = OUTPUT (o-acts);
//                         w>8 idle.
//   Wave 1 (w 16..31): A: 2 rows {48+2(w-16),+1} (rows 48..79)
//                      B: 2 rows {2(w-16),+1} (rows 0..31).
//   Weight slots wS[4][20] f2 (union, 160 floats -- same budget as R10).
//   Sum order: even/odd partial accumulators per row (acc.x/acc.y) -- absmax
//   proven sum-order-invariant across R10-R14 (bf16-dataset output quantum
//   2^-11 dominates).

#define B_SZ 4096
#define T_SZ 1024
#define HID  40

typedef unsigned short u16;
typedef unsigned int   u32;
typedef float f2 __attribute__((ext_vector_type(2)));

__device__ __forceinline__ float bf2f(u16 v) {
  union { u32 u; float f; } c; c.u = ((u32)v) << 16; return c.f;
}

template <bool BF>
__device__ __forceinline__ float ldg(const void* p, long i) {
  if (BF) return bf2f(((const u16*)p)[i]);
  return ((const float*)p)[i];
}

template <bool BF>
__device__ __forceinline__ f2 ldg2(const void* p, long i) {
  f2 r;
  r.x = ldg<BF>(p, i + 0);
  r.y = ldg<BF>(p, i + 1);
  return r;
}

// Proven rounds 3-14: true-bf16 weights all have |w| <= 1/sqrt(41) ~ 0.156;
// fp32 data read as bf16 halfwords exceeds 0.2 with P ~ 1-1e-10.
__device__ __forceinline__ bool detect_bf16(const void* w) {
  const u16* p = (const u16*)w;
  bool bf = true;
  for (int i = 0; i < 64; ++i) {
    float f = bf2f(p[i]);
    if (!(fabsf(f) <= 0.2f)) bf = false;
  }
  return bf;
}

template <bool BF>
__global__ __launch_bounds__(128, 2)
void rnn_kernel(const void* __restrict__ inp,
                const void* __restrict__ h2h_w1, const void* __restrict__ h2h_b1,
                const void* __restrict__ h2h_w2, const void* __restrict__ h2h_b2,
                const void* __restrict__ h2o_w1, const void* __restrict__ h2o_b1,
                const void* __restrict__ h2o_w2, const void* __restrict__ h2o_b2,
                void* __restrict__ out) {
  __shared__ __align__(16) float sH[4][44];  // [el][k]  (176 B stride)
  __shared__ __align__(16) float sA[4][84];  // [el][j]  (336 B stride)

  if (detect_bf16(h2h_w1) != BF) return;  // wrong-dtype instantiation exits

  const int tid  = threadIdx.x;
  const int lane = tid & 63;
  const int wv   = tid >> 6;                // 0..1 (wave-uniform)
  const int el   = lane & 3;
  const int w    = wv * 16 + (lane >> 2);   // 0..31

  // Row maps (coverage: A rows 0..79 exactly once; B rows 0..40 exactly once)
  const int a0 = (wv == 0) ? 3 * w : 48 + 2 * (w - 16);
  const int nA = (wv == 0) ? 3 : 2;
  const int rB = (wv == 0) ? ((w < 8) ? 32 + w : ((w == 8) ? 40 : -1)) : 2 * (w - 16);

  // ---- Load this thread's 4 weight row-slots (f2 pairs, union as R10) ----
  f2    wS[4][20];
  float wu[3] = {0, 0, 0}, ba[3] = {0, 0, 0}, bb[2] = {0, 0};
#pragma unroll
  for (int q = 0; q < 3; ++q) {
    if (q < nA) {
      const int  j  = a0 + q;
      const bool hh = (j < HID);
      const void* wb1 = hh ? h2h_w1 : h2o_w1;
      const long  jr  = hh ? j : (j - HID);
      wu[q] = ldg<BF>(wb1, jr * 41);
      ba[q] = ldg<BF>(hh ? h2h_b1 : h2o_b1, jr);
#pragma unroll
      for (int i = 0; i < 20; ++i)
        wS[q][i] = ldg2<BF>(wb1, jr * 41 + 1 + 2 * i);
    }
  }
  if (wv == 0) {
    if (rB >= 0) {
      const bool isout = (rB == 40);
      const void* wb2 = isout ? h2o_w2 : h2h_w2;
      const long  rr  = isout ? 0 : rB;
      bb[0] = isout ? ldg<BF>(h2o_b2, 0) : ldg<BF>(h2h_b2, rB);
#pragma unroll
      for (int i = 0; i < 20; ++i)
        wS[3][i] = ldg2<BF>(wb2, rr * 40 + 2 * i);
    }
  } else {
#pragma unroll
    for (int q = 0; q < 2; ++q) {
      const long r = rB + q;
      bb[q] = ldg<BF>(h2h_b2, r);
#pragma unroll
      for (int i = 0; i < 20; ++i)
        wS[2 + q][i] = ldg2<BF>(h2h_w2, r * 40 + 2 * i);
    }
  }

  for (int i = tid; i < 4 * 44; i += 128) ((float*)sH)[i] = 0.f;
  __syncthreads();

  const int  b    = blockIdx.x * 4 + el;
  const long base = (long)b * T_SZ;
  float u_cur = ldg<BF>(inp, base);

  for (int t = 0; t < T_SZ; ++t) {
    const float u_nxt = (t + 1 < T_SZ) ? ldg<BF>(inp, base + t + 1) : 0.f;

    // ---------- Phase A: layer 1 (80 neurons), packed f32 ----------
    f2 hv[20];
    {
      const f2* hp = (const f2*)sH[el];   // 16B-aligned: merges to b128 reads
#pragma unroll
      for (int i = 0; i < 20; ++i) hv[i] = hp[i];
    }
#pragma unroll
    for (int q = 0; q < 3; ++q) {
      if (q < nA) {   // wave-uniform
        f2 acc = {0.f, 0.f};
#pragma unroll
        for (int i = 0; i < 20; ++i)
          acc = hv[i] * wS[q][i] + acc;   // contracts to v_pk_fma_f32
        const float a = fmaf(u_cur, wu[q], ba[q]) + acc.x + acc.y;
        sA[el][a0 + q] = fmaxf(a, 0.01f * a);   // LeakyReLU(0.01)
      }
    }
    __syncthreads();   // sA visible; all sH reads done

    // ---------- Phase B: layer 2 (rows 0..39 = hidden, 40 = output) ----------
    if (wv == 1) {     // uniform: 2 rows, a-acts
      f2 av[20];
      {
        const f2* ap = (const f2*)sA[el];
#pragma unroll
        for (int i = 0; i < 20; ++i) av[i] = ap[i];
      }
#pragma unroll
      for (int q = 0; q < 2; ++q) {
        f2 acc = {0.f, 0.f};
#pragma unroll
        for (int i = 0; i < 20; ++i)
          acc = av[i] * wS[2 + q][i] + acc;
        sH[el][rB + q] = bb[q] + acc.x + acc.y;
      }
    } else if (rB >= 0) {   // wave 0: one row (32..39) or output row 40
      const f2* ap = (const f2*)(&sA[el][(rB == 40) ? 40 : 0]);  // 16B-aligned
      f2 av[20];
#pragma unroll
      for (int i = 0; i < 20; ++i) av[i] = ap[i];
      f2 acc = {0.f, 0.f};
#pragma unroll
      for (int i = 0; i < 20; ++i)
        acc = av[i] * wS[3][i] + acc;
      const float a2 = bb[0] + acc.x + acc.y;
      if (rB < HID) {
        sH[el][rB] = a2;
      } else {
        if (BF) ((__hip_bfloat16*)out)[base + t] = __float2bfloat16(a2);
        else    ((float*)out)[base + t] = a2;
      }
    }
    __syncthreads();   // sH update + sA reads done before next step

    u_cur = u_nxt;
  }
}

extern "C" void kernel_launch(void* const* d_in, const int* in_sizes, int n_in,
                              void* d_out, int out_size, void* d_ws, size_t ws_size,
                              hipStream_t stream) {
  (void)in_sizes; (void)n_in; (void)out_size; (void)d_ws; (void)ws_size;
  rnn_kernel<false><<<dim3(B_SZ / 4), dim3(128), 0, stream>>>(
      d_in[0], d_in[1], d_in[2], d_in[3], d_in[4],
      d_in[5], d_in[6], d_in[7], d_in[8], d_out);
  rnn_kernel<true><<<dim3(B_SZ / 4), dim3(128), 0, stream>>>(
      d_in[0], d_in[1], d_in[2], d_in[3], d_in[4],
      d_in[5], d_in[6], d_in[7], d_in[8], d_out);
}